// Round 13
// baseline (357.399 us; speedup 1.0000x reference)
//
#include <hip/hip_runtime.h>
#include <math.h>

// ============================================================================
// Round 13 (= Round 12 with compile fix): knn v6 — instruction-count surgery.
// (1) d = fma(-2,dot,s) [bitwise == s - 2*dot]; (2) pass A candidate loads
// via uniform float16-vector -> s_load_dwordx16; (3) bitonic xor1/xor2 via
// DPP quad_perm. FIX: bsxu now uses literal DPP ctrl per branch (builtin
// requires constant integer). Selection bit-identical. Rest = Round 11.
// ============================================================================

#define EPSBN 1e-5f

typedef _Float16 v8h  __attribute__((ext_vector_type(8)));
typedef _Float16 v4h  __attribute__((ext_vector_type(4)));
typedef float    v16f __attribute__((ext_vector_type(16)));
typedef float    v16x __attribute__((ext_vector_type(16)));

// ---- ws layout (float offsets) ----
#define W0T_OFF   0         // [3][64]
#define B0_OFF    192
#define W1T_OFF   256       // [64][64]
#define B1_OFF    4352
#define A0XT_OFF  4416      // [3][64]
#define A0FT_OFF  4608      // [64][64]
#define BA0_OFF   8704
#define A1T_OFF   8768      // fp16 frag-linear a1 image (8192 halfs)
#define BA1_OFF   16960
#define A2T_OFF   17088     // fp16 frag-linear a2 image (16384 halfs)
#define BA2_OFF   33472
#define C2T_OFF   33600     // fp16 frag-linear c2 image: 8192 float4
#define C3H_OFF   66368     // fp16 frag-linear c3 image: 4096 float4
#define BC2_OFF   99136
#define BC3_OFF   132160
#define C4T_OFF   132288    // [128][6] fp32
#define BC4_OFF   133056
#define PTS4_OFF  133120    // [32768] float4 {x,y,z,sq}
#define Q_OFF     264192    // [32768][64]
#define C_OFF     2361344   // [32768][64]
#define IDX_OFF   4458496   // [32768][16] int (batch-local m)
#define LOCAL_OFF 4982784   // [32768][128]
#define GF_OFF    9177088   // [8][128]

// ---------------------------------------------------------------------------
// Kernel 0: fold BN into weights.
// ---------------------------------------------------------------------------
__device__ __forceinline__ void fold_one(int e, const float* w, const float* b,
    const float* g, const float* t, const float* m, const float* v,
    float* wt, float* bo, int O, int Cfull, int cbeg)
{
    int o = e % O, c = e / O;
    float s = 1.0f;
    if (g) s = g[o] * (1.0f / sqrtf(v[o] + EPSBN));
    wt[c * O + o] = w[o * Cfull + cbeg + c] * s;
    if (c == 0 && bo) {
        float bias = b[o];
        if (g) bias = (bias - m[o]) * s + t[o];
        bo[o] = bias;
    }
}

__global__ __launch_bounds__(256) void fold_kernel(
    const float* c0w, const float* c0b, const float* c0g, const float* c0t, const float* c0m, const float* c0v,
    const float* c1w, const float* c1b, const float* c1g, const float* c1t, const float* c1m, const float* c1v,
    const float* a0w, const float* a0b, const float* a0g, const float* a0t, const float* a0m, const float* a0v,
    const float* a1w, const float* a1b, const float* a1g, const float* a1t, const float* a1m, const float* a1v,
    const float* a2w, const float* a2b, const float* a2g, const float* a2t, const float* a2m, const float* a2v,
    const float* c2w, const float* c2b, const float* c2g, const float* c2t, const float* c2m, const float* c2v,
    const float* c3w, const float* c3b, const float* c3g, const float* c3t, const float* c3m, const float* c3v,
    const float* c4w, const float* c4b,
    float* ws)
{
    int e = blockIdx.x * 256 + threadIdx.x;
    if (e < 192)        { fold_one(e,          c0w, c0b, c0g, c0t, c0m, c0v, ws + W0T_OFF,  ws + B0_OFF,  64, 3,   0); return; }
    e -= 192;
    if (e < 4096)       { fold_one(e,          c1w, c1b, c1g, c1t, c1m, c1v, ws + W1T_OFF,  ws + B1_OFF,  64, 64,  0); return; }
    e -= 4096;
    if (e < 192)        { fold_one(e,          a0w, a0b, a0g, a0t, a0m, a0v, ws + A0XT_OFF, ws + BA0_OFF, 64, 67,  0); return; }
    e -= 192;
    if (e < 4096)       { fold_one(e,          a0w, a0b, a0g, a0t, a0m, a0v, ws + A0FT_OFF, nullptr,      64, 67,  3); return; }
    e -= 4096;
    if (e < 8192) {
        int j = e & 7, l = (e >> 3) & 63, kf = (e >> 9) & 3, wv = e >> 11;
        int o = wv * 32 + (l & 31);
        int c = kf * 16 + (l >> 5) * 8 + j;
        float s = a1g[o] * (1.0f / sqrtf(a1v[o] + EPSBN));
        ((_Float16*)(ws + A1T_OFF))[e] = (_Float16)(a1w[o * 64 + c] * s);
        if (c == 0) ws[BA1_OFF + o] = (a1b[o] - a1m[o]) * s + a1t[o];
        return;
    }
    e -= 8192;
    if (e < 16384) {
        int j = e & 7, l = (e >> 3) & 63, kf = (e >> 9) & 7, wv = e >> 12;
        int o = wv * 32 + (l & 31);
        int c = kf * 16 + (l >> 5) * 8 + j;
        float s = a2g[o] * (1.0f / sqrtf(a2v[o] + EPSBN));
        ((_Float16*)(ws + A2T_OFF))[e] = (_Float16)(a2w[o * 128 + c] * s);
        if (c == 0) ws[BA2_OFF + o] = (a2b[o] - a2m[o]) * s + a2t[o];
        return;
    }
    e -= 16384;
    if (e < 65536) {
        int j = e & 7, l = (e >> 3) & 63, s5 = (e >> 9) & 15, ot = e >> 13;
        int o = ot * 32 + (l & 31);
        int c = s5 * 16 + (l >> 5) * 8 + j;
        float sc = c2g[o] * (1.0f / sqrtf(c2v[o] + EPSBN));
        ((_Float16*)(ws + C2T_OFF))[e] = (_Float16)(c2w[o * 256 + c] * sc);
        if (c == 0) ws[BC2_OFF + o] = (c2b[o] - c2m[o]) * sc + c2t[o];
        return;
    }
    e -= 65536;
    if (e < 32768) {
        int j = e & 7, l = (e >> 3) & 63, s5 = (e >> 9) & 15, ot = e >> 13;
        int o = ot * 32 + (l & 31);
        int c = s5 * 16 + (l >> 5) * 8 + j;
        float sc = c3g[o] * (1.0f / sqrtf(c3v[o] + EPSBN));
        ((_Float16*)(ws + C3H_OFF))[e] = (_Float16)(c3w[o * 256 + c] * sc);
        if (c == 0) ws[BC3_OFF + o] = (c3b[o] - c3m[o]) * sc + c3t[o];
        return;
    }
    e -= 32768;
    if (e < 768)        { fold_one(e,          c4w, c4b, nullptr, nullptr, nullptr, nullptr, ws + C4T_OFF, ws + BC4_OFF, 6, 128, 0); return; }
}

// ---------------------------------------------------------------------------
// Kernel 1: per-point MLP 3->64->64 (+ pts4 with exact sq, + q/c for a0 trick)
// ---------------------------------------------------------------------------
__global__ __launch_bounds__(256) void point_mlp_kernel(const float* __restrict__ pts, float* __restrict__ ws)
{
    __shared__ float sh[4][64];
    __shared__ float sx[4][64];
    int lane = threadIdx.x & 63;
    int wv = threadIdx.x >> 6;
    int pid = blockIdx.x * 4 + wv;
    const float* p = pts + pid * 3;
    float x = p[0], y = p[1], z = p[2];
    if (lane == 0) {
        float sq = __fadd_rn(__fadd_rn(__fmul_rn(x, x), __fmul_rn(y, y)), __fmul_rn(z, z));
        ((float4*)(ws + PTS4_OFF))[pid] = make_float4(x, y, z, sq);
    }
    const float* W0T  = ws + W0T_OFF;
    const float* B0   = ws + B0_OFF;
    const float* W1T  = ws + W1T_OFF;
    const float* B1   = ws + B1_OFF;
    const float* A0XT = ws + A0XT_OFF;
    const float* A0FT = ws + A0FT_OFF;
    const float* BA0  = ws + BA0_OFF;

    float h0 = B0[lane];
    h0 = fmaf(x, W0T[lane], h0);
    h0 = fmaf(y, W0T[64 + lane], h0);
    h0 = fmaf(z, W0T[128 + lane], h0);
    h0 = fmaxf(h0, 0.0f);
    sh[wv][lane] = h0;
    __syncthreads();

    float acc = B1[lane];
    #pragma unroll 8
    for (int c = 0; c < 64; ++c) acc = fmaf(W1T[c * 64 + lane], sh[wv][c], acc);
    float x1 = fmaxf(acc, 0.0f);
    sx[wv][lane] = x1;

    float q = __fmul_rn(x, A0XT[lane]);
    q = fmaf(y, A0XT[64 + lane], q);
    q = fmaf(z, A0XT[128 + lane], q);
    ws[Q_OFF + pid * 64 + lane] = q;
    __syncthreads();

    float cacc = q + BA0[lane];
    #pragma unroll 8
    for (int c = 0; c < 64; ++c) cacc = fmaf(A0FT[c * 64 + lane], sx[wv][c], cacc);
    ws[C_OFF + pid * 64 + lane] = cacc;
}

// ---------------------------------------------------------------------------
// Kernel 2 (v6): exact kNN. fma-folded dist (bitwise == reference form),
// s_load_dwordx16 pass A, DPP xor1/xor2 in bitonics.
// ---------------------------------------------------------------------------
__device__ __forceinline__ float dist2_ref(float xn, float yn, float zn, float sqn, float4 pm)
{
    float dot = __fmul_rn(xn, pm.x);
    dot = __fmaf_rn(yn, pm.y, dot);
    dot = __fmaf_rn(zn, pm.z, dot);
    float s = __fadd_rn(sqn, pm.w);
    // fma(-2,dot,s) == s - round(2*dot) bitwise: 2*dot is exact in fp32.
    return __fmaf_rn(-2.0f, dot, s);
}

__device__ __forceinline__ float bsxf(float v, int j)
{
    if (j == 1) return __int_as_float(__builtin_amdgcn_update_dpp(0, __float_as_int(v), 0xB1, 0xF, 0xF, true));
    if (j == 2) return __int_as_float(__builtin_amdgcn_update_dpp(0, __float_as_int(v), 0x4E, 0xF, 0xF, true));
    return __shfl_xor(v, j);
}

__device__ __forceinline__ unsigned long long bsxu(unsigned long long v, int j)
{
    if (j == 1) {
        unsigned lo = (unsigned)__builtin_amdgcn_update_dpp(0, (int)(unsigned)v, 0xB1, 0xF, 0xF, true);
        unsigned hi = (unsigned)__builtin_amdgcn_update_dpp(0, (int)(unsigned)(v >> 32), 0xB1, 0xF, 0xF, true);
        return ((unsigned long long)hi << 32) | lo;
    }
    if (j == 2) {
        unsigned lo = (unsigned)__builtin_amdgcn_update_dpp(0, (int)(unsigned)v, 0x4E, 0xF, 0xF, true);
        unsigned hi = (unsigned)__builtin_amdgcn_update_dpp(0, (int)(unsigned)(v >> 32), 0x4E, 0xF, 0xF, true);
        return ((unsigned long long)hi << 32) | lo;
    }
    return __shfl_xor(v, j);
}

#define KNN_CAP 64
__global__ __launch_bounds__(1024) void knn_kernel(float* __restrict__ ws)
{
    __shared__ float gmins[64 * 65];          // 16.6KB
    __shared__ float bufd[16][72];            // per-wave (d) buffer
    __shared__ int   bufi[16][72];            // per-wave (idx) buffer
    __shared__ int   cnt[64];                 // per-row count (fallback check)

    const float4* __restrict__ pts4 = (const float4*)(ws + PTS4_OFF);
    int* IDX = (int*)(ws + IDX_OFF);

    const int l     = threadIdx.x & 63;       // lane; = row in pass A
    const int row   = l;
    const int wvu   = __builtin_amdgcn_readfirstlane(threadIdx.x >> 6); // 0..15
    const int base  = (blockIdx.x >> 6) << 12;
    const int rbase = blockIdx.x * 64;
    const int r     = rbase + row;

    float4 pn = pts4[r];
    float xn = pn.x, yn = pn.y, zn = pn.z, sqn = pn.w;

    // ---- Pass A: wave wvu scans its 256 candidates in 4 groups of 64.
    //      Candidates via uniform 64B loads (s_load_dwordx16 = 4 cands).
    #pragma unroll
    for (int g = 0; g < 4; ++g) {
        const v16x* __restrict__ cp16 = (const v16x*)(pts4 + base + wvu * 256 + g * 64);
        float mn0 = INFINITY, mn1 = INFINITY, mn2 = INFINITY, mn3 = INFINITY;
        #pragma unroll
        for (int i = 0; i < 16; ++i) {
            v16x b = cp16[i];
            {
                float dot = __fmul_rn(xn, b[0]);
                dot = __fmaf_rn(yn, b[1], dot);
                dot = __fmaf_rn(zn, b[2], dot);
                float s = __fadd_rn(sqn, b[3]);
                mn0 = fminf(mn0, __fmaf_rn(-2.0f, dot, s));
            }
            {
                float dot = __fmul_rn(xn, b[4]);
                dot = __fmaf_rn(yn, b[5], dot);
                dot = __fmaf_rn(zn, b[6], dot);
                float s = __fadd_rn(sqn, b[7]);
                mn1 = fminf(mn1, __fmaf_rn(-2.0f, dot, s));
            }
            {
                float dot = __fmul_rn(xn, b[8]);
                dot = __fmaf_rn(yn, b[9], dot);
                dot = __fmaf_rn(zn, b[10], dot);
                float s = __fadd_rn(sqn, b[11]);
                mn2 = fminf(mn2, __fmaf_rn(-2.0f, dot, s));
            }
            {
                float dot = __fmul_rn(xn, b[12]);
                dot = __fmaf_rn(yn, b[13], dot);
                dot = __fmaf_rn(zn, b[14], dot);
                float s = __fadd_rn(sqn, b[15]);
                mn3 = fminf(mn3, __fmaf_rn(-2.0f, dot, s));
            }
        }
        gmins[row * 65 + wvu * 4 + g] = fminf(fminf(mn0, mn1), fminf(mn2, mn3));
    }
    __syncthreads();   // the ONLY barrier before the fallback check

    // ---- Wave-local: rows rw = wvu*4 .. wvu*4+3, end-to-end per row.
    for (int rr = 0; rr < 4; ++rr) {
        int rw = wvu * 4 + rr;
        float gm = gmins[rw * 65 + l];        // lane = group id

        // tau = 17th smallest of 64 group minima (register bitonic, ascending)
        float v = gm;
        #pragma unroll
        for (int k = 2; k <= 64; k <<= 1) {
            #pragma unroll
            for (int j = k >> 1; j > 0; j >>= 1) {
                float o = bsxf(v, j);
                bool mx = (((l & j) != 0) == ((l & k) == 0));
                v = mx ? fmaxf(v, o) : fminf(v, o);
            }
        }
        float tv = __shfl(v, 16);             // broadcast rank-16 value

        // qualifying groups: min <= tau (exact superset of all d<=tau cands)
        unsigned long long qm = __ballot(gm <= tv);

        // row point (wave-uniform)
        float4 pr = pts4[rbase + rw];
        float xr = pr.x, yr = pr.y, zr = pr.z, sr = pr.w;

        // filtered scan: lane = candidate within group, coalesced vector loads
        int cr = 0;
        while (qm) {
            int g = __ffsll((unsigned long long)qm) - 1;
            qm &= qm - 1;
            int ci = g * 64 + l;
            float d = dist2_ref(xr, yr, zr, sr, pts4[base + ci]);
            bool p = (d <= tv);
            unsigned long long mk = __ballot(p);
            int my = __builtin_amdgcn_mbcnt_hi((unsigned)(mk >> 32),
                     __builtin_amdgcn_mbcnt_lo((unsigned)mk, 0));
            int slot = cr + my;
            if (p && slot < KNN_CAP) { bufd[wvu][slot] = d; bufi[wvu][slot] = ci; }
            cr += (int)__popcll(mk);
        }
        if (l == 0) cnt[rw] = cr;

        // extraction: bitonic sort (d,idx) keys, lanes 0..15 emit top-16
        if (cr <= KNN_CAP) {
            unsigned long long key = ~0ULL;
            if (l < cr) {
                unsigned u = __float_as_uint(bufd[wvu][l]);
                u = (u & 0x80000000u) ? ~u : (u | 0x80000000u);
                key = ((unsigned long long)u << 32) | (unsigned)bufi[wvu][l];
            }
            #pragma unroll
            for (int k = 2; k <= 64; k <<= 1) {
                #pragma unroll
                for (int j = k >> 1; j > 0; j >>= 1) {
                    unsigned long long o = bsxu(key, j);
                    bool mx = (((l & j) != 0) == ((l & k) == 0));
                    key = mx ? (key > o ? key : o) : (key < o ? key : o);
                }
            }
            if (l < 16)
                IDX[(rbase + rw) * 16 + l] = (int)(key & 0xFFFFFFFFu);
        }
    }
    __syncthreads();

    // overflow fallback (practically never): exact serial top-16, lane = row
    if (threadIdx.x < 64 && cnt[threadIdx.x] > KNN_CAP) {
        int* out = IDX + (rbase + threadIdx.x) * 16;
        float hd[16]; int hi[16];
        #pragma unroll
        for (int t2 = 0; t2 < 16; ++t2) { hd[t2] = INFINITY; hi[t2] = 0; }
        for (int mm = 0; mm < 4096; ++mm) {
            float d = dist2_ref(xn, yn, zn, sqn, pts4[base + mm]);
            if (d < hd[15]) {
                float vd = d; int vi = mm;
                #pragma unroll
                for (int t2 = 0; t2 < 16; ++t2) {
                    bool sm = vd < hd[t2];
                    float td = hd[t2]; int ti = hi[t2];
                    if (sm) { hd[t2] = vd; hi[t2] = vi; vd = td; vi = ti; }
                }
            }
        }
        for (int jj = 0; jj < 16; ++jj) out[jj] = hi[jj];
    }
}

// ---------------------------------------------------------------------------
// Kernel 3 (v3d): a1+a2 fp16 MFMA + FUSED global-feature atomicMax epilogue.
// ---------------------------------------------------------------------------
__device__ __forceinline__ float max16_dpp(float v)
{
    int vi = __float_as_int(v);
    v = fmaxf(v, __int_as_float(__builtin_amdgcn_update_dpp(0, vi, 0xB1, 0xf, 0xf, true)));  // quad_perm [1,0,3,2]
    vi = __float_as_int(v);
    v = fmaxf(v, __int_as_float(__builtin_amdgcn_update_dpp(0, vi, 0x4E, 0xf, 0xf, true)));  // quad_perm [2,3,0,1]
    vi = __float_as_int(v);
    v = fmaxf(v, __int_as_float(__builtin_amdgcn_update_dpp(0, vi, 0x141, 0xf, 0xf, true))); // row_half_mirror
    vi = __float_as_int(v);
    v = fmaxf(v, __int_as_float(__builtin_amdgcn_update_dpp(0, vi, 0x140, 0xf, 0xf, true))); // row_mirror
    return v;
}

__device__ __forceinline__ void nbr_stage_g1(
    _Float16* sG1, const float* Cf, const float* Qf,
    int t, int gpt0, int g, int base, int m)
{
    int r = t >> 2, cs = t & 3;
    int gpt = gpt0 + g * 4 + (r >> 4);
    const float4* crow = (const float4*)(Cf + (size_t)(base + m) * 64) + cs * 4;
    const float4* qrow = (const float4*)(Qf + (size_t)gpt * 64) + cs * 4;
    v8h h0, h1;
    #pragma unroll
    for (int u = 0; u < 2; ++u) {
        float4 cv = crow[u], qv = qrow[u];
        h0[u * 4 + 0] = (_Float16)fmaxf(cv.x - qv.x, 0.0f);
        h0[u * 4 + 1] = (_Float16)fmaxf(cv.y - qv.y, 0.0f);
        h0[u * 4 + 2] = (_Float16)fmaxf(cv.z - qv.z, 0.0f);
        h0[u * 4 + 3] = (_Float16)fmaxf(cv.w - qv.w, 0.0f);
    }
    #pragma unroll
    for (int u = 0; u < 2; ++u) {
        float4 cv = crow[2 + u], qv = qrow[2 + u];
        h1[u * 4 + 0] = (_Float16)fmaxf(cv.x - qv.x, 0.0f);
        h1[u * 4 + 1] = (_Float16)fmaxf(cv.y - qv.y, 0.0f);
        h1[u * 4 + 2] = (_Float16)fmaxf(cv.z - qv.z, 0.0f);
        h1[u * 4 + 3] = (_Float16)fmaxf(cv.w - qv.w, 0.0f);
    }
    int rs = r & 7;
    *(v8h*)&sG1[r * 64 + ((cs * 2    ) ^ rs) * 8] = h0;
    *(v8h*)&sG1[r * 64 + ((cs * 2 + 1) ^ rs) * 8] = h1;
}

__global__ __launch_bounds__(256) void nbr_mlp_mfma_kernel(float* __restrict__ ws)
{
    __shared__ __align__(16) unsigned char smem[33792];
    _Float16* sG1   = (_Float16*)smem;               // [64][64]h swz   8KB
    _Float16* sH1   = (_Float16*)(smem + 8192);      // [64][128]h swz 16KB
    float*    sPool = (float*)(smem + 24576);        // [16][128]f      8KB
    float*    sB1   = (float*)(smem + 32768);        // [128]f biases a1
    float*    sB2   = (float*)(smem + 33280);        // [128]f biases a2

    const int t   = threadIdx.x;
    const int l   = t & 63;
    const int w   = t >> 6;
    const int ln  = l & 31;
    const int hi  = l >> 5;
    const int blk = blockIdx.x;
    const int gpt0 = blk * 16;
    const int base = (blk >> 8) << 12;

    const float* Cf = ws + C_OFF;
    const float* Qf = ws + Q_OFF;
    const int* IDX = (const int*)(ws + IDX_OFF);

    // stage biases to LDS (replaces 32 persistent VGPRs)
    if (t < 128) sB1[t] = ws[BA1_OFF + t];
    else         sB2[t - 128] = ws[BA2_OFF + (t - 128)];

    // prefetch all 4 groups' neighbor indices (this thread's row r = t>>2)
    int mi[4];
    {
        int r = t >> 2;
        #pragma unroll
        for (int g = 0; g < 4; ++g)
            mi[g] = IDX[(gpt0 + g * 4 + (r >> 4)) * 16 + (r & 15)];
    }

    // weight fragments DIRECT from frag-linear global images (L2-resident)
    v8h fa[4], fa2[8];
    {
        const float4* a1img = (const float4*)(ws + A1T_OFF);
        const float4* a2img = (const float4*)(ws + A2T_OFF);
        #pragma unroll
        for (int kf = 0; kf < 4; ++kf) {
            float4 tmp = a1img[(w * 4 + kf) * 64 + l];
            fa[kf] = *(v8h*)&tmp;
        }
        #pragma unroll
        for (int kf = 0; kf < 8; ++kf) {
            float4 tmp = a2img[(w * 8 + kf) * 64 + l];
            fa2[kf] = *(v8h*)&tmp;
        }
    }

    nbr_stage_g1(sG1, Cf, Qf, t, gpt0, 0, base, mi[0]);
    __syncthreads();

    for (int g = 0; g < 4; ++g) {
        // ---- a1: sG1 -> sH1 ----
        #pragma unroll
        for (int rt = 0; rt < 2; ++rt) {
            int r = rt * 32 + ln, rs = r & 7;
            v16f acc;
            #pragma unroll
            for (int i = 0; i < 16; ++i) acc[i] = 0.0f;
            #pragma unroll
            for (int kf = 0; kf < 4; ++kf) {
                v8h fb = *(const v8h*)&sG1[r * 64 + ((kf * 2 + hi) ^ rs) * 8];
                acc = __builtin_amdgcn_mfma_f32_32x32x16_f16(fa[kf], fb, acc, 0, 0, 0);
            }
            #pragma unroll
            for (int q = 0; q < 4; ++q) {
                float4 b4 = *(const float4*)&sB1[w * 32 + 8 * q + 4 * hi];
                v4h hv;
                hv[0] = (_Float16)fmaxf(acc[q * 4 + 0] + b4.x, 0.0f);
                hv[1] = (_Float16)fmaxf(acc[q * 4 + 1] + b4.y, 0.0f);
                hv[2] = (_Float16)fmaxf(acc[q * 4 + 2] + b4.z, 0.0f);
                hv[3] = (_Float16)fmaxf(acc[q * 4 + 3] + b4.w, 0.0f);
                int gg = w * 4 + q;
                *(v4h*)&sH1[r * 128 + ((gg ^ rs) * 8) + 4 * hi] = hv;
            }
        }
        __syncthreads();

        // prefetch next group's G1 (gather latency overlaps a2 MFMAs)
        if (g < 3) nbr_stage_g1(sG1, Cf, Qf, t, gpt0, g + 1, base, mi[g + 1]);

        // ---- a2: sH1 -> pooled sPool rows (DPP maxpool) ----
        #pragma unroll
        for (int rt = 0; rt < 2; ++rt) {
            int r = rt * 32 + ln, rs = r & 7;
            v16f acc;
            #pragma unroll
            for (int i = 0; i < 16; ++i) acc[i] = 0.0f;
            #pragma unroll
            for (int kf = 0; kf < 8; ++kf) {
                v8h fb = *(const v8h*)&sH1[r * 128 + ((kf * 2 + hi) ^ rs) * 8];
                acc = __builtin_amdgcn_mfma_f32_32x32x16_f16(fa2[kf], fb, acc, 0, 0, 0);
            }
            #pragma unroll
            for (int i = 0; i < 16; ++i) acc[i] = max16_dpp(acc[i]);
            if ((l & 15) == 0) {
                int p = g * 4 + rt * 2 + ((l >> 4) & 1);
                #pragma unroll
                for (int q = 0; q < 4; ++q) {
                    float4 b4 = *(const float4*)&sB2[w * 32 + 8 * q + 4 * hi];
                    float4 o4;
                    o4.x = fmaxf(acc[q * 4 + 0] + b4.x, 0.0f);
                    o4.y = fmaxf(acc[q * 4 + 1] + b4.y, 0.0f);
                    o4.z = fmaxf(acc[q * 4 + 2] + b4.z, 0.0f);
                    o4.w = fmaxf(acc[q * 4 + 3] + b4.w, 0.0f);
                    int ob = w * 32 + 8 * q + 4 * hi;
                    *(float4*)&sPool[p * 128 + ob] = o4;
                }
            }
        }
        __syncthreads();
    }

    // coalesced burst write: 16 points x 128 ch = 512 float4
    {
        float* LOCAL = ws + LOCAL_OFF;
        const float4* sp4 = (const float4*)sPool;
        #pragma unroll
        for (int u = 0; u < 2; ++u) {
            int e = t + 256 * u;
            int pp = e >> 5, cc = e & 31;
            ((float4*)&LOCAL[(size_t)(gpt0 + pp) * 128])[cc] = sp4[e];
        }
    }

    // fused global-feature: block-local 16-point max + 1 atomic per channel
    if (t < 128) {
        float m = 0.0f;
        #pragma unroll
        for (int p = 0; p < 16; ++p) m = fmaxf(m, sPool[p * 128 + t]);
        atomicMax((int*)(ws + GF_OFF) + (blk >> 8) * 128 + t, __float_as_int(m));
    }
}

// ---------------------------------------------------------------------------
// Kernel 5: head c2/c3 fp16 MFMA + c4 fp32 (unchanged — verified).
// ---------------------------------------------------------------------------
__global__ __launch_bounds__(256) void head_mfma_kernel(float* __restrict__ ws, float* __restrict__ out)
{
    __shared__ __align__(16) unsigned char smem[66560];
    _Float16* sF  = (_Float16*)smem;
    float*    sF3 = (float*)smem;
    _Float16* sF2 = (_Float16*)(smem + 33792);

    const int t  = threadIdx.x;
    const int l  = t & 63;
    const int w  = t >> 6;
    const int ln = l & 31;
    const int hi = l >> 5;
    const int gpt0 = blockIdx.x * 64;
    const int b = blockIdx.x >> 6;

    const float4* c2h = (const float4*)(ws + C2T_OFF);
    const float4* c3h = (const float4*)(ws + C3H_OFF);

    {
        int m = t >> 2, cs = t & 3;
        const float4* src = (cs < 2)
            ? (const float4*)(ws + LOCAL_OFF + (size_t)(gpt0 + m) * 128) + cs * 16
            : (const float4*)(ws + GF_OFF + b * 128) + (cs - 2) * 16;
        int c0 = cs * 64;
        #pragma unroll
        for (int u = 0; u < 8; ++u) {
            float4 a0 = src[u * 2], a1 = src[u * 2 + 1];
            v8h h;
            h[0] = (_Float16)a0.x; h[1] = (_Float16)a0.y;
            h[2] = (_Float16)a0.z; h[3] = (_Float16)a0.w;
            h[4] = (_Float16)a1.x; h[5] = (_Float16)a1.y;
            h[6] = (_Float16)a1.z; h[7] = (_Float16)a1.w;
            int g = ((c0 >> 3) + u) ^ (m & 31);
            *(v8h*)&sF[m * 256 + g * 8] = h;
        }
    }
    __syncthreads();

    #pragma unroll
    for (int ot = 0; ot < 2; ++ot) {
        int ot2 = 2 * w + ot;
        v8h fa[16];
        #pragma unroll
        for (int s = 0; s < 16; ++s) {
            float4 tmp = c2h[(ot2 * 16 + s) * 64 + l];
            fa[s] = *(v8h*)&tmp;
        }
        float b2[16];
        #pragma unroll
        for (int i = 0; i < 16; ++i)
            b2[i] = ws[BC2_OFF + ot2 * 32 + (i & 3) + 8 * (i >> 2) + 4 * hi];
        #pragma unroll
        for (int mt = 0; mt < 2; ++mt) {
            int m = mt * 32 + ln;
            v16f acc;
            #pragma unroll
            for (int i = 0; i < 16; ++i) acc[i] = 0.0f;
            #pragma unroll
            for (int s = 0; s < 16; ++s) {
                v8h fb = *(const v8h*)&sF[m * 256 + (((2 * s + hi) ^ ln) * 8)];
                acc = __builtin_amdgcn_mfma_f32_32x32x16_f16(fa[s], fb, acc, 0, 0, 0);
            }
            #pragma unroll
            for (int q = 0; q < 4; ++q) {
                v4h hv;
                #pragma unroll
                for (int j = 0; j < 4; ++j)
                    hv[j] = (_Float16)fmaxf(acc[q * 4 + j] + b2[q * 4 + j], 0.0f);
                *(v4h*)&sF2[m * 256 + (((ot2 * 4 + q) ^ ln) * 8) + 4 * hi] = hv;
            }
        }
    }
    __syncthreads();

    {
        v8h fa[16];
        #pragma unroll
        for (int s = 0; s < 16; ++s) {
            float4 tmp = c3h[(w * 16 + s) * 64 + l];
            fa[s] = *(v8h*)&tmp;
        }
        float b3[16];
        #pragma unroll
        for (int i = 0; i < 16; ++i)
            b3[i] = ws[BC3_OFF + w * 32 + (i & 3) + 8 * (i >> 2) + 4 * hi];
        #pragma unroll
        for (int mt = 0; mt < 2; ++mt) {
            int m = mt * 32 + ln;
            v16f acc;
            #pragma unroll
            for (int i = 0; i < 16; ++i) acc[i] = 0.0f;
            #pragma unroll
            for (int s = 0; s < 16; ++s) {
                v8h fb = *(const v8h*)&sF2[m * 256 + (((2 * s + hi) ^ ln) * 8)];
                acc = __builtin_amdgcn_mfma_f32_32x32x16_f16(fa[s], fb, acc, 0, 0, 0);
            }
            #pragma unroll
            for (int q = 0; q < 4; ++q) {
                float4 hv;
                hv.x = fmaxf(acc[q * 4 + 0] + b3[q * 4 + 0], 0.0f);
                hv.y = fmaxf(acc[q * 4 + 1] + b3[q * 4 + 1], 0.0f);
                hv.z = fmaxf(acc[q * 4 + 2] + b3[q * 4 + 2], 0.0f);
                hv.w = fmaxf(acc[q * 4 + 3] + b3[q * 4 + 3], 0.0f);
                *(float4*)&sF3[m * 132 + w * 32 + q * 8 + 4 * hi] = hv;
            }
        }
    }
    __syncthreads();

    const float* C4T = ws + C4T_OFF;
    for (int mo = t; mo < 384; mo += 256) {
        int m = mo / 6, o = mo - m * 6;
        float a = ws[BC4_OFF + o];
        const float4* f4 = (const float4*)(sF3 + m * 132);
        #pragma unroll 8
        for (int kq = 0; kq < 32; ++kq) {
            float4 f = f4[kq];
            a = fmaf(f.x, C4T[(kq * 4 + 0) * 6 + o], a);
            a = fmaf(f.y, C4T[(kq * 4 + 1) * 6 + o], a);
            a = fmaf(f.z, C4T[(kq * 4 + 2) * 6 + o], a);
            a = fmaf(f.w, C4T[(kq * 4 + 3) * 6 + o], a);
        }
        out[(size_t)(gpt0 + m) * 6 + o] = a;
    }
}

// ---------------------------------------------------------------------------
extern "C" void kernel_launch(void* const* d_in, const int* in_sizes, int n_in,
                              void* d_out, int out_size, void* d_ws, size_t ws_size,
                              hipStream_t stream)
{
    const float* pts = (const float*)d_in[0];
    float* ws = (float*)d_ws;
    float* out = (float*)d_out;

    hipMemsetAsync(ws + GF_OFF, 0, 1024 * sizeof(float), stream);

    fold_kernel<<<517, 256, 0, stream>>>(
        (const float*)d_in[1],  (const float*)d_in[2],  (const float*)d_in[3],  (const float*)d_in[4],  (const float*)d_in[5],  (const float*)d_in[6],
        (const float*)d_in[7],  (const float*)d_in[8],  (const float*)d_in[9],  (const float*)d_in[10], (const float*)d_in[11], (const float*)d_in[12],
        (const float*)d_in[13], (const float*)d_in[14], (const float*)d_in[15], (const float*)d_in[16], (const float*)d_in[17], (const float*)d_in[18],
        (const float*)d_in[19], (const float*)d_in[20], (const float*)d_in[21], (const float*)d_in[22], (const float*)d_in[23], (const float*)d_in[24],
        (const float*)d_in[25], (const float*)d_in[26], (const float*)d_in[27], (const float*)d_in[28], (const float*)d_in[29], (const float*)d_in[30],
        (const float*)d_in[31], (const float*)d_in[32], (const float*)d_in[33], (const float*)d_in[34], (const float*)d_in[35], (const float*)d_in[36],
        (const float*)d_in[37], (const float*)d_in[38], (const float*)d_in[39], (const float*)d_in[40], (const float*)d_in[41], (const float*)d_in[42],
        (const float*)d_in[43], (const float*)d_in[44],
        ws);

    point_mlp_kernel<<<8192, 256, 0, stream>>>(pts, ws);
    knn_kernel<<<512, 1024, 0, stream>>>(ws);
    nbr_mlp_mfma_kernel<<<2048, 256, 0, stream>>>(ws);
    head_mfma_kernel<<<512, 256, 0, stream>>>(ws, out);
}

// Round 14
// 356.054 us; speedup vs baseline: 1.0038x; 1.0038x over previous
//
#include <hip/hip_runtime.h>
#include <math.h>

// ============================================================================
// Round 14: (1) knn reverted to Round-11 form (proven 81.6us; R12's dwordx16
// pinned 16 SGPRs/load and throttled the SMEM pipeline -> regression), keeping
// only the bitwise-identical fma fold. (2) point_mlp v2: 16 pts/block, weights
// staged to LDS once (was 32KB of L2 weight stream PER POINT ~ 1GB total),
// sh broadcasts -> __shfl readlane. Arithmetic order identical -> bit-same.
// ============================================================================

#define EPSBN 1e-5f

typedef _Float16 v8h  __attribute__((ext_vector_type(8)));
typedef _Float16 v4h  __attribute__((ext_vector_type(4)));
typedef float    v16f __attribute__((ext_vector_type(16)));

// ---- ws layout (float offsets) ----
#define W0T_OFF   0         // [3][64]
#define B0_OFF    192
#define W1T_OFF   256       // [64][64]
#define B1_OFF    4352
#define A0XT_OFF  4416      // [3][64]
#define A0FT_OFF  4608      // [64][64]
#define BA0_OFF   8704
#define A1T_OFF   8768      // fp16 frag-linear a1 image (8192 halfs)
#define BA1_OFF   16960
#define A2T_OFF   17088     // fp16 frag-linear a2 image (16384 halfs)
#define BA2_OFF   33472
#define C2T_OFF   33600     // fp16 frag-linear c2 image: 8192 float4
#define C3H_OFF   66368     // fp16 frag-linear c3 image: 4096 float4
#define BC2_OFF   99136
#define BC3_OFF   132160
#define C4T_OFF   132288    // [128][6] fp32
#define BC4_OFF   133056
#define PTS4_OFF  133120    // [32768] float4 {x,y,z,sq}
#define Q_OFF     264192    // [32768][64]
#define C_OFF     2361344   // [32768][64]
#define IDX_OFF   4458496   // [32768][16] int (batch-local m)
#define LOCAL_OFF 4982784   // [32768][128]
#define GF_OFF    9177088   // [8][128]

// ---------------------------------------------------------------------------
// Kernel 0: fold BN into weights.
// ---------------------------------------------------------------------------
__device__ __forceinline__ void fold_one(int e, const float* w, const float* b,
    const float* g, const float* t, const float* m, const float* v,
    float* wt, float* bo, int O, int Cfull, int cbeg)
{
    int o = e % O, c = e / O;
    float s = 1.0f;
    if (g) s = g[o] * (1.0f / sqrtf(v[o] + EPSBN));
    wt[c * O + o] = w[o * Cfull + cbeg + c] * s;
    if (c == 0 && bo) {
        float bias = b[o];
        if (g) bias = (bias - m[o]) * s + t[o];
        bo[o] = bias;
    }
}

__global__ __launch_bounds__(256) void fold_kernel(
    const float* c0w, const float* c0b, const float* c0g, const float* c0t, const float* c0m, const float* c0v,
    const float* c1w, const float* c1b, const float* c1g, const float* c1t, const float* c1m, const float* c1v,
    const float* a0w, const float* a0b, const float* a0g, const float* a0t, const float* a0m, const float* a0v,
    const float* a1w, const float* a1b, const float* a1g, const float* a1t, const float* a1m, const float* a1v,
    const float* a2w, const float* a2b, const float* a2g, const float* a2t, const float* a2m, const float* a2v,
    const float* c2w, const float* c2b, const float* c2g, const float* c2t, const float* c2m, const float* c2v,
    const float* c3w, const float* c3b, const float* c3g, const float* c3t, const float* c3m, const float* c3v,
    const float* c4w, const float* c4b,
    float* ws)
{
    int e = blockIdx.x * 256 + threadIdx.x;
    if (e < 192)        { fold_one(e,          c0w, c0b, c0g, c0t, c0m, c0v, ws + W0T_OFF,  ws + B0_OFF,  64, 3,   0); return; }
    e -= 192;
    if (e < 4096)       { fold_one(e,          c1w, c1b, c1g, c1t, c1m, c1v, ws + W1T_OFF,  ws + B1_OFF,  64, 64,  0); return; }
    e -= 4096;
    if (e < 192)        { fold_one(e,          a0w, a0b, a0g, a0t, a0m, a0v, ws + A0XT_OFF, ws + BA0_OFF, 64, 67,  0); return; }
    e -= 192;
    if (e < 4096)       { fold_one(e,          a0w, a0b, a0g, a0t, a0m, a0v, ws + A0FT_OFF, nullptr,      64, 67,  3); return; }
    e -= 4096;
    if (e < 8192) {
        int j = e & 7, l = (e >> 3) & 63, kf = (e >> 9) & 3, wv = e >> 11;
        int o = wv * 32 + (l & 31);
        int c = kf * 16 + (l >> 5) * 8 + j;
        float s = a1g[o] * (1.0f / sqrtf(a1v[o] + EPSBN));
        ((_Float16*)(ws + A1T_OFF))[e] = (_Float16)(a1w[o * 64 + c] * s);
        if (c == 0) ws[BA1_OFF + o] = (a1b[o] - a1m[o]) * s + a1t[o];
        return;
    }
    e -= 8192;
    if (e < 16384) {
        int j = e & 7, l = (e >> 3) & 63, kf = (e >> 9) & 7, wv = e >> 12;
        int o = wv * 32 + (l & 31);
        int c = kf * 16 + (l >> 5) * 8 + j;
        float s = a2g[o] * (1.0f / sqrtf(a2v[o] + EPSBN));
        ((_Float16*)(ws + A2T_OFF))[e] = (_Float16)(a2w[o * 128 + c] * s);
        if (c == 0) ws[BA2_OFF + o] = (a2b[o] - a2m[o]) * s + a2t[o];
        return;
    }
    e -= 16384;
    if (e < 65536) {
        int j = e & 7, l = (e >> 3) & 63, s5 = (e >> 9) & 15, ot = e >> 13;
        int o = ot * 32 + (l & 31);
        int c = s5 * 16 + (l >> 5) * 8 + j;
        float sc = c2g[o] * (1.0f / sqrtf(c2v[o] + EPSBN));
        ((_Float16*)(ws + C2T_OFF))[e] = (_Float16)(c2w[o * 256 + c] * sc);
        if (c == 0) ws[BC2_OFF + o] = (c2b[o] - c2m[o]) * sc + c2t[o];
        return;
    }
    e -= 65536;
    if (e < 32768) {
        int j = e & 7, l = (e >> 3) & 63, s5 = (e >> 9) & 15, ot = e >> 13;
        int o = ot * 32 + (l & 31);
        int c = s5 * 16 + (l >> 5) * 8 + j;
        float sc = c3g[o] * (1.0f / sqrtf(c3v[o] + EPSBN));
        ((_Float16*)(ws + C3H_OFF))[e] = (_Float16)(c3w[o * 256 + c] * sc);
        if (c == 0) ws[BC3_OFF + o] = (c3b[o] - c3m[o]) * sc + c3t[o];
        return;
    }
    e -= 32768;
    if (e < 768)        { fold_one(e,          c4w, c4b, nullptr, nullptr, nullptr, nullptr, ws + C4T_OFF, ws + BC4_OFF, 6, 128, 0); return; }
}

// ---------------------------------------------------------------------------
// Kernel 1 (v2): per-point MLP, 16 pts/block, weights staged to LDS once.
// Arithmetic order identical to v1 -> bit-identical pts4/Q/C.
// ---------------------------------------------------------------------------
__global__ __launch_bounds__(256) void point_mlp_kernel(const float* __restrict__ pts, float* __restrict__ ws)
{
    __shared__ __align__(16) float sW1f[4096];   // 16KB W1T image [c][o]
    __shared__ __align__(16) float sA0f[4096];   // 16KB A0FT image [c][o]
    const int t = threadIdx.x;
    const int lane = t & 63;
    const int wv = t >> 6;

    {
        const float4* w1 = (const float4*)(ws + W1T_OFF);
        const float4* a0 = (const float4*)(ws + A0FT_OFF);
        float4* d1 = (float4*)sW1f;
        float4* d2 = (float4*)sA0f;
        #pragma unroll
        for (int u = 0; u < 4; ++u) {
            d1[t + 256 * u] = w1[t + 256 * u];
            d2[t + 256 * u] = a0[t + 256 * u];
        }
    }
    const float b0l  = (ws + B0_OFF)[lane];
    const float b1l  = (ws + B1_OFF)[lane];
    const float ba0l = (ws + BA0_OFF)[lane];
    const float w0x = (ws + W0T_OFF)[lane];
    const float w0y = (ws + W0T_OFF)[64 + lane];
    const float w0z = (ws + W0T_OFF)[128 + lane];
    const float axx = (ws + A0XT_OFF)[lane];
    const float axy = (ws + A0XT_OFF)[64 + lane];
    const float axz = (ws + A0XT_OFF)[128 + lane];
    __syncthreads();

    for (int pp = 0; pp < 4; ++pp) {
        int pid = blockIdx.x * 16 + wv * 4 + pp;
        const float* p = pts + (size_t)pid * 3;
        float x = p[0], y = p[1], z = p[2];
        if (lane == 0) {
            float sq = __fadd_rn(__fadd_rn(__fmul_rn(x, x), __fmul_rn(y, y)), __fmul_rn(z, z));
            ((float4*)(ws + PTS4_OFF))[pid] = make_float4(x, y, z, sq);
        }
        float h0 = b0l;
        h0 = fmaf(x, w0x, h0);
        h0 = fmaf(y, w0y, h0);
        h0 = fmaf(z, w0z, h0);
        h0 = fmaxf(h0, 0.0f);

        float acc = b1l;
        #pragma unroll
        for (int c = 0; c < 64; ++c)
            acc = fmaf(sW1f[c * 64 + lane], __shfl(h0, c), acc);
        float x1 = fmaxf(acc, 0.0f);

        float q = __fmul_rn(x, axx);
        q = fmaf(y, axy, q);
        q = fmaf(z, axz, q);
        ws[Q_OFF + (size_t)pid * 64 + lane] = q;

        float cacc = q + ba0l;
        #pragma unroll
        for (int c = 0; c < 64; ++c)
            cacc = fmaf(sA0f[c * 64 + lane], __shfl(x1, c), cacc);
        ws[C_OFF + (size_t)pid * 64 + lane] = cacc;
    }
}

// ---------------------------------------------------------------------------
// Kernel 2 (R11 form + fma fold): exact kNN, wave-local selection,
// 16 waves/block, float4 scalar candidate loads, shfl_xor bitonics.
// ---------------------------------------------------------------------------
__device__ __forceinline__ float dist2_ref(float xn, float yn, float zn, float sqn, float4 pm)
{
    float dot = __fmul_rn(xn, pm.x);
    dot = __fmaf_rn(yn, pm.y, dot);
    dot = __fmaf_rn(zn, pm.z, dot);
    float s = __fadd_rn(sqn, pm.w);
    // fma(-2,dot,s) == s - round(2*dot) bitwise: 2*dot is exact in fp32.
    return __fmaf_rn(-2.0f, dot, s);
}

#define KNN_CAP 64
__global__ __launch_bounds__(1024) void knn_kernel(float* __restrict__ ws)
{
    __shared__ float gmins[64 * 65];          // 16.6KB
    __shared__ float bufd[16][72];            // per-wave (d) buffer
    __shared__ int   bufi[16][72];            // per-wave (idx) buffer
    __shared__ int   cnt[64];                 // per-row count (fallback check)

    const float4* __restrict__ pts4 = (const float4*)(ws + PTS4_OFF);
    int* IDX = (int*)(ws + IDX_OFF);

    const int l     = threadIdx.x & 63;       // lane; = row in pass A
    const int row   = l;
    const int wvu   = __builtin_amdgcn_readfirstlane(threadIdx.x >> 6); // 0..15
    const int base  = (blockIdx.x >> 6) << 12;
    const int rbase = blockIdx.x * 64;
    const int r     = rbase + row;

    float4 pn = pts4[r];
    float xn = pn.x, yn = pn.y, zn = pn.z, sqn = pn.w;

    // ---- Pass A: wave wvu scans its 256 candidates in 4 groups of 64,
    //      computing group minima for all 64 rows (lane = row), scalar loads.
    #pragma unroll
    for (int g = 0; g < 4; ++g) {
        const float4* __restrict__ cp = pts4 + base + wvu * 256 + g * 64;
        float mn0 = INFINITY, mn1 = INFINITY, mn2 = INFINITY, mn3 = INFINITY;
        #pragma unroll 4
        for (int i = 0; i < 64; i += 4) {
            mn0 = fminf(mn0, dist2_ref(xn, yn, zn, sqn, cp[i + 0]));
            mn1 = fminf(mn1, dist2_ref(xn, yn, zn, sqn, cp[i + 1]));
            mn2 = fminf(mn2, dist2_ref(xn, yn, zn, sqn, cp[i + 2]));
            mn3 = fminf(mn3, dist2_ref(xn, yn, zn, sqn, cp[i + 3]));
        }
        gmins[row * 65 + wvu * 4 + g] = fminf(fminf(mn0, mn1), fminf(mn2, mn3));
    }
    __syncthreads();   // the ONLY barrier before the fallback check

    // ---- Wave-local: rows rw = wvu*4 .. wvu*4+3, end-to-end per row.
    for (int rr = 0; rr < 4; ++rr) {
        int rw = wvu * 4 + rr;
        float gm = gmins[rw * 65 + l];        // lane = group id

        // tau = 17th smallest of 64 group minima (register bitonic, ascending)
        float v = gm;
        #pragma unroll
        for (int k = 2; k <= 64; k <<= 1) {
            #pragma unroll
            for (int j = k >> 1; j > 0; j >>= 1) {
                float o = __shfl_xor(v, j);
                bool mx = (((l & j) != 0) == ((l & k) == 0));
                v = mx ? fmaxf(v, o) : fminf(v, o);
            }
        }
        float tv = __shfl(v, 16);             // broadcast rank-16 value

        // qualifying groups: min <= tau (exact superset of all d<=tau cands)
        unsigned long long qm = __ballot(gm <= tv);

        // row point (wave-uniform)
        float4 pr = pts4[rbase + rw];
        float xr = pr.x, yr = pr.y, zr = pr.z, sr = pr.w;

        // filtered scan: lane = candidate within group, coalesced vector loads
        int cr = 0;
        while (qm) {
            int g = __ffsll((unsigned long long)qm) - 1;
            qm &= qm - 1;
            int ci = g * 64 + l;
            float d = dist2_ref(xr, yr, zr, sr, pts4[base + ci]);
            bool p = (d <= tv);
            unsigned long long mk = __ballot(p);
            int my = __builtin_amdgcn_mbcnt_hi((unsigned)(mk >> 32),
                     __builtin_amdgcn_mbcnt_lo((unsigned)mk, 0));
            int slot = cr + my;
            if (p && slot < KNN_CAP) { bufd[wvu][slot] = d; bufi[wvu][slot] = ci; }
            cr += (int)__popcll(mk);
        }
        if (l == 0) cnt[rw] = cr;

        // extraction: bitonic sort (d,idx) keys, lanes 0..15 emit top-16
        if (cr <= KNN_CAP) {
            unsigned long long key = ~0ULL;
            if (l < cr) {
                unsigned u = __float_as_uint(bufd[wvu][l]);
                u = (u & 0x80000000u) ? ~u : (u | 0x80000000u);
                key = ((unsigned long long)u << 32) | (unsigned)bufi[wvu][l];
            }
            #pragma unroll
            for (int k = 2; k <= 64; k <<= 1) {
                #pragma unroll
                for (int j = k >> 1; j > 0; j >>= 1) {
                    unsigned long long o = __shfl_xor(key, j);
                    bool mx = (((l & j) != 0) == ((l & k) == 0));
                    key = mx ? (key > o ? key : o) : (key < o ? key : o);
                }
            }
            if (l < 16)
                IDX[(rbase + rw) * 16 + l] = (int)(key & 0xFFFFFFFFu);
        }
    }
    __syncthreads();

    // overflow fallback (practically never): exact serial top-16, lane = row
    if (threadIdx.x < 64 && cnt[threadIdx.x] > KNN_CAP) {
        int* out = IDX + (rbase + threadIdx.x) * 16;
        float hd[16]; int hi[16];
        #pragma unroll
        for (int t2 = 0; t2 < 16; ++t2) { hd[t2] = INFINITY; hi[t2] = 0; }
        for (int mm = 0; mm < 4096; ++mm) {
            float d = dist2_ref(xn, yn, zn, sqn, pts4[base + mm]);
            if (d < hd[15]) {
                float vd = d; int vi = mm;
                #pragma unroll
                for (int t2 = 0; t2 < 16; ++t2) {
                    bool sm = vd < hd[t2];
                    float td = hd[t2]; int ti = hi[t2];
                    if (sm) { hd[t2] = vd; hi[t2] = vi; vd = td; vi = ti; }
                }
            }
        }
        for (int jj = 0; jj < 16; ++jj) out[jj] = hi[jj];
    }
}

// ---------------------------------------------------------------------------
// Kernel 3 (v3d): a1+a2 fp16 MFMA + FUSED global-feature atomicMax epilogue.
// ---------------------------------------------------------------------------
__device__ __forceinline__ float max16_dpp(float v)
{
    int vi = __float_as_int(v);
    v = fmaxf(v, __int_as_float(__builtin_amdgcn_update_dpp(0, vi, 0xB1, 0xf, 0xf, true)));  // quad_perm [1,0,3,2]
    vi = __float_as_int(v);
    v = fmaxf(v, __int_as_float(__builtin_amdgcn_update_dpp(0, vi, 0x4E, 0xf, 0xf, true)));  // quad_perm [2,3,0,1]
    vi = __float_as_int(v);
    v = fmaxf(v, __int_as_float(__builtin_amdgcn_update_dpp(0, vi, 0x141, 0xf, 0xf, true))); // row_half_mirror
    vi = __float_as_int(v);
    v = fmaxf(v, __int_as_float(__builtin_amdgcn_update_dpp(0, vi, 0x140, 0xf, 0xf, true))); // row_mirror
    return v;
}

__device__ __forceinline__ void nbr_stage_g1(
    _Float16* sG1, const float* Cf, const float* Qf,
    int t, int gpt0, int g, int base, int m)
{
    int r = t >> 2, cs = t & 3;
    int gpt = gpt0 + g * 4 + (r >> 4);
    const float4* crow = (const float4*)(Cf + (size_t)(base + m) * 64) + cs * 4;
    const float4* qrow = (const float4*)(Qf + (size_t)gpt * 64) + cs * 4;
    v8h h0, h1;
    #pragma unroll
    for (int u = 0; u < 2; ++u) {
        float4 cv = crow[u], qv = qrow[u];
        h0[u * 4 + 0] = (_Float16)fmaxf(cv.x - qv.x, 0.0f);
        h0[u * 4 + 1] = (_Float16)fmaxf(cv.y - qv.y, 0.0f);
        h0[u * 4 + 2] = (_Float16)fmaxf(cv.z - qv.z, 0.0f);
        h0[u * 4 + 3] = (_Float16)fmaxf(cv.w - qv.w, 0.0f);
    }
    #pragma unroll
    for (int u = 0; u < 2; ++u) {
        float4 cv = crow[2 + u], qv = qrow[2 + u];
        h1[u * 4 + 0] = (_Float16)fmaxf(cv.x - qv.x, 0.0f);
        h1[u * 4 + 1] = (_Float16)fmaxf(cv.y - qv.y, 0.0f);
        h1[u * 4 + 2] = (_Float16)fmaxf(cv.z - qv.z, 0.0f);
        h1[u * 4 + 3] = (_Float16)fmaxf(cv.w - qv.w, 0.0f);
    }
    int rs = r & 7;
    *(v8h*)&sG1[r * 64 + ((cs * 2    ) ^ rs) * 8] = h0;
    *(v8h*)&sG1[r * 64 + ((cs * 2 + 1) ^ rs) * 8] = h1;
}

__global__ __launch_bounds__(256) void nbr_mlp_mfma_kernel(float* __restrict__ ws)
{
    __shared__ __align__(16) unsigned char smem[33792];
    _Float16* sG1   = (_Float16*)smem;               // [64][64]h swz   8KB
    _Float16* sH1   = (_Float16*)(smem + 8192);      // [64][128]h swz 16KB
    float*    sPool = (float*)(smem + 24576);        // [16][128]f      8KB
    float*    sB1   = (float*)(smem + 32768);        // [128]f biases a1
    float*    sB2   = (float*)(smem + 33280);        // [128]f biases a2

    const int t   = threadIdx.x;
    const int l   = t & 63;
    const int w   = t >> 6;
    const int ln  = l & 31;
    const int hi  = l >> 5;
    const int blk = blockIdx.x;
    const int gpt0 = blk * 16;
    const int base = (blk >> 8) << 12;

    const float* Cf = ws + C_OFF;
    const float* Qf = ws + Q_OFF;
    const int* IDX = (const int*)(ws + IDX_OFF);

    // stage biases to LDS (replaces 32 persistent VGPRs)
    if (t < 128) sB1[t] = ws[BA1_OFF + t];
    else         sB2[t - 128] = ws[BA2_OFF + (t - 128)];

    // prefetch all 4 groups' neighbor indices (this thread's row r = t>>2)
    int mi[4];
    {
        int r = t >> 2;
        #pragma unroll
        for (int g = 0; g < 4; ++g)
            mi[g] = IDX[(gpt0 + g * 4 + (r >> 4)) * 16 + (r & 15)];
    }

    // weight fragments DIRECT from frag-linear global images (L2-resident)
    v8h fa[4], fa2[8];
    {
        const float4* a1img = (const float4*)(ws + A1T_OFF);
        const float4* a2img = (const float4*)(ws + A2T_OFF);
        #pragma unroll
        for (int kf = 0; kf < 4; ++kf) {
            float4 tmp = a1img[(w * 4 + kf) * 64 + l];
            fa[kf] = *(v8h*)&tmp;
        }
        #pragma unroll
        for (int kf = 0; kf < 8; ++kf) {
            float4 tmp = a2img[(w * 8 + kf) * 64 + l];
            fa2[kf] = *(v8h*)&tmp;
        }
    }

    nbr_stage_g1(sG1, Cf, Qf, t, gpt0, 0, base, mi[0]);
    __syncthreads();

    for (int g = 0; g < 4; ++g) {
        // ---- a1: sG1 -> sH1 ----
        #pragma unroll
        for (int rt = 0; rt < 2; ++rt) {
            int r = rt * 32 + ln, rs = r & 7;
            v16f acc;
            #pragma unroll
            for (int i = 0; i < 16; ++i) acc[i] = 0.0f;
            #pragma unroll
            for (int kf = 0; kf < 4; ++kf) {
                v8h fb = *(const v8h*)&sG1[r * 64 + ((kf * 2 + hi) ^ rs) * 8];
                acc = __builtin_amdgcn_mfma_f32_32x32x16_f16(fa[kf], fb, acc, 0, 0, 0);
            }
            #pragma unroll
            for (int q = 0; q < 4; ++q) {
                float4 b4 = *(const float4*)&sB1[w * 32 + 8 * q + 4 * hi];
                v4h hv;
                hv[0] = (_Float16)fmaxf(acc[q * 4 + 0] + b4.x, 0.0f);
                hv[1] = (_Float16)fmaxf(acc[q * 4 + 1] + b4.y, 0.0f);
                hv[2] = (_Float16)fmaxf(acc[q * 4 + 2] + b4.z, 0.0f);
                hv[3] = (_Float16)fmaxf(acc[q * 4 + 3] + b4.w, 0.0f);
                int gg = w * 4 + q;
                *(v4h*)&sH1[r * 128 + ((gg ^ rs) * 8) + 4 * hi] = hv;
            }
        }
        __syncthreads();

        // prefetch next group's G1 (gather latency overlaps a2 MFMAs)
        if (g < 3) nbr_stage_g1(sG1, Cf, Qf, t, gpt0, g + 1, base, mi[g + 1]);

        // ---- a2: sH1 -> pooled sPool rows (DPP maxpool) ----
        #pragma unroll
        for (int rt = 0; rt < 2; ++rt) {
            int r = rt * 32 + ln, rs = r & 7;
            v16f acc;
            #pragma unroll
            for (int i = 0; i < 16; ++i) acc[i] = 0.0f;
            #pragma unroll
            for (int kf = 0; kf < 8; ++kf) {
                v8h fb = *(const v8h*)&sH1[r * 128 + ((kf * 2 + hi) ^ rs) * 8];
                acc = __builtin_amdgcn_mfma_f32_32x32x16_f16(fa2[kf], fb, acc, 0, 0, 0);
            }
            #pragma unroll
            for (int i = 0; i < 16; ++i) acc[i] = max16_dpp(acc[i]);
            if ((l & 15) == 0) {
                int p = g * 4 + rt * 2 + ((l >> 4) & 1);
                #pragma unroll
                for (int q = 0; q < 4; ++q) {
                    float4 b4 = *(const float4*)&sB2[w * 32 + 8 * q + 4 * hi];
                    float4 o4;
                    o4.x = fmaxf(acc[q * 4 + 0] + b4.x, 0.0f);
                    o4.y = fmaxf(acc[q * 4 + 1] + b4.y, 0.0f);
                    o4.z = fmaxf(acc[q * 4 + 2] + b4.z, 0.0f);
                    o4.w = fmaxf(acc[q * 4 + 3] + b4.w, 0.0f);
                    int ob = w * 32 + 8 * q + 4 * hi;
                    *(float4*)&sPool[p * 128 + ob] = o4;
                }
            }
        }
        __syncthreads();
    }

    // coalesced burst write: 16 points x 128 ch = 512 float4
    {
        float* LOCAL = ws + LOCAL_OFF;
        const float4* sp4 = (const float4*)sPool;
        #pragma unroll
        for (int u = 0; u < 2; ++u) {
            int e = t + 256 * u;
            int pp = e >> 5, cc = e & 31;
            ((float4*)&LOCAL[(size_t)(gpt0 + pp) * 128])[cc] = sp4[e];
        }
    }

    // fused global-feature: block-local 16-point max + 1 atomic per channel
    if (t < 128) {
        float m = 0.0f;
        #pragma unroll
        for (int p = 0; p < 16; ++p) m = fmaxf(m, sPool[p * 128 + t]);
        atomicMax((int*)(ws + GF_OFF) + (blk >> 8) * 128 + t, __float_as_int(m));
    }
}

// ---------------------------------------------------------------------------
// Kernel 5: head c2/c3 fp16 MFMA + c4 fp32 (unchanged — verified).
// ---------------------------------------------------------------------------
__global__ __launch_bounds__(256) void head_mfma_kernel(float* __restrict__ ws, float* __restrict__ out)
{
    __shared__ __align__(16) unsigned char smem[66560];
    _Float16* sF  = (_Float16*)smem;
    float*    sF3 = (float*)smem;
    _Float16* sF2 = (_Float16*)(smem + 33792);

    const int t  = threadIdx.x;
    const int l  = t & 63;
    const int w  = t >> 6;
    const int ln = l & 31;
    const int hi = l >> 5;
    const int gpt0 = blockIdx.x * 64;
    const int b = blockIdx.x >> 6;

    const float4* c2h = (const float4*)(ws + C2T_OFF);
    const float4* c3h = (const float4*)(ws + C3H_OFF);

    {
        int m = t >> 2, cs = t & 3;
        const float4* src = (cs < 2)
            ? (const float4*)(ws + LOCAL_OFF + (size_t)(gpt0 + m) * 128) + cs * 16
            : (const float4*)(ws + GF_OFF + b * 128) + (cs - 2) * 16;
        int c0 = cs * 64;
        #pragma unroll
        for (int u = 0; u < 8; ++u) {
            float4 a0 = src[u * 2], a1 = src[u * 2 + 1];
            v8h h;
            h[0] = (_Float16)a0.x; h[1] = (_Float16)a0.y;
            h[2] = (_Float16)a0.z; h[3] = (_Float16)a0.w;
            h[4] = (_Float16)a1.x; h[5] = (_Float16)a1.y;
            h[6] = (_Float16)a1.z; h[7] = (_Float16)a1.w;
            int g = ((c0 >> 3) + u) ^ (m & 31);
            *(v8h*)&sF[m * 256 + g * 8] = h;
        }
    }
    __syncthreads();

    #pragma unroll
    for (int ot = 0; ot < 2; ++ot) {
        int ot2 = 2 * w + ot;
        v8h fa[16];
        #pragma unroll
        for (int s = 0; s < 16; ++s) {
            float4 tmp = c2h[(ot2 * 16 + s) * 64 + l];
            fa[s] = *(v8h*)&tmp;
        }
        float b2[16];
        #pragma unroll
        for (int i = 0; i < 16; ++i)
            b2[i] = ws[BC2_OFF + ot2 * 32 + (i & 3) + 8 * (i >> 2) + 4 * hi];
        #pragma unroll
        for (int mt = 0; mt < 2; ++mt) {
            int m = mt * 32 + ln;
            v16f acc;
            #pragma unroll
            for (int i = 0; i < 16; ++i) acc[i] = 0.0f;
            #pragma unroll
            for (int s = 0; s < 16; ++s) {
                v8h fb = *(const v8h*)&sF[m * 256 + (((2 * s + hi) ^ ln) * 8)];
                acc = __builtin_amdgcn_mfma_f32_32x32x16_f16(fa[s], fb, acc, 0, 0, 0);
            }
            #pragma unroll
            for (int q = 0; q < 4; ++q) {
                v4h hv;
                #pragma unroll
                for (int j = 0; j < 4; ++j)
                    hv[j] = (_Float16)fmaxf(acc[q * 4 + j] + b2[q * 4 + j], 0.0f);
                *(v4h*)&sF2[m * 256 + (((ot2 * 4 + q) ^ ln) * 8) + 4 * hi] = hv;
            }
        }
    }
    __syncthreads();

    {
        v8h fa[16];
        #pragma unroll
        for (int s = 0; s < 16; ++s) {
            float4 tmp = c3h[(w * 16 + s) * 64 + l];
            fa[s] = *(v8h*)&tmp;
        }
        float b3[16];
        #pragma unroll
        for (int i = 0; i < 16; ++i)
            b3[i] = ws[BC3_OFF + w * 32 + (i & 3) + 8 * (i >> 2) + 4 * hi];
        #pragma unroll
        for (int mt = 0; mt < 2; ++mt) {
            int m = mt * 32 + ln;
            v16f acc;
            #pragma unroll
            for (int i = 0; i < 16; ++i) acc[i] = 0.0f;
            #pragma unroll
            for (int s = 0; s < 16; ++s) {
                v8h fb = *(const v8h*)&sF2[m * 256 + (((2 * s + hi) ^ ln) * 8)];
                acc = __builtin_amdgcn_mfma_f32_32x32x16_f16(fa[s], fb, acc, 0, 0, 0);
            }
            #pragma unroll
            for (int q = 0; q < 4; ++q) {
                float4 hv;
                hv.x = fmaxf(acc[q * 4 + 0] + b3[q * 4 + 0], 0.0f);
                hv.y = fmaxf(acc[q * 4 + 1] + b3[q * 4 + 1], 0.0f);
                hv.z = fmaxf(acc[q * 4 + 2] + b3[q * 4 + 2], 0.0f);
                hv.w = fmaxf(acc[q * 4 + 3] + b3[q * 4 + 3], 0.0f);
                *(float4*)&sF3[m * 132 + w * 32 + q * 8 + 4 * hi] = hv;
            }
        }
    }
    __syncthreads();

    const float* C4T = ws + C4T_OFF;
    for (int mo = t; mo < 384; mo += 256) {
        int m = mo / 6, o = mo - m * 6;
        float a = ws[BC4_OFF + o];
        const float4* f4 = (const float4*)(sF3 + m * 132);
        #pragma unroll 8
        for (int kq = 0; kq < 32; ++kq) {
            float4 f = f4[kq];
            a = fmaf(f.x, C4T[(kq * 4 + 0) * 6 + o], a);
            a = fmaf(f.y, C4T[(kq * 4 + 1) * 6 + o], a);
            a = fmaf(f.z, C4T[(kq * 4 + 2) * 6 + o], a);
            a = fmaf(f.w, C4T[(kq * 4 + 3) * 6 + o], a);
        }
        out[(size_t)(gpt0 + m) * 6 + o] = a;
    }
}

// ---------------------------------------------------------------------------
extern "C" void kernel_launch(void* const* d_in, const int* in_sizes, int n_in,
                              void* d_out, int out_size, void* d_ws, size_t ws_size,
                              hipStream_t stream)
{
    const float* pts = (const float*)d_in[0];
    float* ws = (float*)d_ws;
    float* out = (float*)d_out;

    hipMemsetAsync(ws + GF_OFF, 0, 1024 * sizeof(float), stream);

    fold_kernel<<<517, 256, 0, stream>>>(
        (const float*)d_in[1],  (const float*)d_in[2],  (const float*)d_in[3],  (const float*)d_in[4],  (const float*)d_in[5],  (const float*)d_in[6],
        (const float*)d_in[7],  (const float*)d_in[8],  (const float*)d_in[9],  (const float*)d_in[10], (const float*)d_in[11], (const float*)d_in[12],
        (const float*)d_in[13], (const float*)d_in[14], (const float*)d_in[15], (const float*)d_in[16], (const float*)d_in[17], (const float*)d_in[18],
        (const float*)d_in[19], (const float*)d_in[20], (const float*)d_in[21], (const float*)d_in[22], (const float*)d_in[23], (const float*)d_in[24],
        (const float*)d_in[25], (const float*)d_in[26], (const float*)d_in[27], (const float*)d_in[28], (const float*)d_in[29], (const float*)d_in[30],
        (const float*)d_in[31], (const float*)d_in[32], (const float*)d_in[33], (const float*)d_in[34], (const float*)d_in[35], (const float*)d_in[36],
        (const float*)d_in[37], (const float*)d_in[38], (const float*)d_in[39], (const float*)d_in[40], (const float*)d_in[41], (const float*)d_in[42],
        (const float*)d_in[43], (const float*)d_in[44],
        ws);

    point_mlp_kernel<<<2048, 256, 0, stream>>>(pts, ws);
    knn_kernel<<<512, 1024, 0, stream>>>(ws);
    nbr_mlp_mfma_kernel<<<2048, 256, 0, stream>>>(ws);
    head_mfma_kernel<<<512, 256, 0, stream>>>(ws, out);
}

// Round 15
// 343.815 us; speedup vs baseline: 1.0395x; 1.0356x over previous
//
#include <hip/hip_runtime.h>
#include <math.h>

// ============================================================================
// Round 15: restore best-known config (R11) + keep knn fma fold + fold the GF
// memset into fold_kernel (one fewer dispatch). point_mlp v2 was a ~8us
// regression (readlane+LDS = 3 ops/MAC vs v1's broadcast ds_read+fma = 2).
// ============================================================================

#define EPSBN 1e-5f

typedef _Float16 v8h  __attribute__((ext_vector_type(8)));
typedef _Float16 v4h  __attribute__((ext_vector_type(4)));
typedef float    v16f __attribute__((ext_vector_type(16)));

// ---- ws layout (float offsets) ----
#define W0T_OFF   0         // [3][64]
#define B0_OFF    192
#define W1T_OFF   256       // [64][64]
#define B1_OFF    4352
#define A0XT_OFF  4416      // [3][64]
#define A0FT_OFF  4608      // [64][64]
#define BA0_OFF   8704
#define A1T_OFF   8768      // fp16 frag-linear a1 image (8192 halfs)
#define BA1_OFF   16960
#define A2T_OFF   17088     // fp16 frag-linear a2 image (16384 halfs)
#define BA2_OFF   33472
#define C2T_OFF   33600     // fp16 frag-linear c2 image: 8192 float4
#define C3H_OFF   66368     // fp16 frag-linear c3 image: 4096 float4
#define BC2_OFF   99136
#define BC3_OFF   132160
#define C4T_OFF   132288    // [128][6] fp32
#define BC4_OFF   133056
#define PTS4_OFF  133120    // [32768] float4 {x,y,z,sq}
#define Q_OFF     264192    // [32768][64]
#define C_OFF     2361344   // [32768][64]
#define IDX_OFF   4458496   // [32768][16] int (batch-local m)
#define LOCAL_OFF 4982784   // [32768][128]
#define GF_OFF    9177088   // [8][128]

// ---------------------------------------------------------------------------
// Kernel 0: fold BN into weights + zero GF (memset dispatch folded in).
// ---------------------------------------------------------------------------
__device__ __forceinline__ void fold_one(int e, const float* w, const float* b,
    const float* g, const float* t, const float* m, const float* v,
    float* wt, float* bo, int O, int Cfull, int cbeg)
{
    int o = e % O, c = e / O;
    float s = 1.0f;
    if (g) s = g[o] * (1.0f / sqrtf(v[o] + EPSBN));
    wt[c * O + o] = w[o * Cfull + cbeg + c] * s;
    if (c == 0 && bo) {
        float bias = b[o];
        if (g) bias = (bias - m[o]) * s + t[o];
        bo[o] = bias;
    }
}

__global__ __launch_bounds__(256) void fold_kernel(
    const float* c0w, const float* c0b, const float* c0g, const float* c0t, const float* c0m, const float* c0v,
    const float* c1w, const float* c1b, const float* c1g, const float* c1t, const float* c1m, const float* c1v,
    const float* a0w, const float* a0b, const float* a0g, const float* a0t, const float* a0m, const float* a0v,
    const float* a1w, const float* a1b, const float* a1g, const float* a1t, const float* a1m, const float* a1v,
    const float* a2w, const float* a2b, const float* a2g, const float* a2t, const float* a2m, const float* a2v,
    const float* c2w, const float* c2b, const float* c2g, const float* c2t, const float* c2m, const float* c2v,
    const float* c3w, const float* c3b, const float* c3g, const float* c3t, const float* c3m, const float* c3v,
    const float* c4w, const float* c4b,
    float* ws)
{
    int e = blockIdx.x * 256 + threadIdx.x;
    if (e < 192)        { fold_one(e,          c0w, c0b, c0g, c0t, c0m, c0v, ws + W0T_OFF,  ws + B0_OFF,  64, 3,   0); return; }
    e -= 192;
    if (e < 4096)       { fold_one(e,          c1w, c1b, c1g, c1t, c1m, c1v, ws + W1T_OFF,  ws + B1_OFF,  64, 64,  0); return; }
    e -= 4096;
    if (e < 192)        { fold_one(e,          a0w, a0b, a0g, a0t, a0m, a0v, ws + A0XT_OFF, ws + BA0_OFF, 64, 67,  0); return; }
    e -= 192;
    if (e < 4096)       { fold_one(e,          a0w, a0b, a0g, a0t, a0m, a0v, ws + A0FT_OFF, nullptr,      64, 67,  3); return; }
    e -= 4096;
    if (e < 8192) {
        int j = e & 7, l = (e >> 3) & 63, kf = (e >> 9) & 3, wv = e >> 11;
        int o = wv * 32 + (l & 31);
        int c = kf * 16 + (l >> 5) * 8 + j;
        float s = a1g[o] * (1.0f / sqrtf(a1v[o] + EPSBN));
        ((_Float16*)(ws + A1T_OFF))[e] = (_Float16)(a1w[o * 64 + c] * s);
        if (c == 0) ws[BA1_OFF + o] = (a1b[o] - a1m[o]) * s + a1t[o];
        return;
    }
    e -= 8192;
    if (e < 16384) {
        int j = e & 7, l = (e >> 3) & 63, kf = (e >> 9) & 7, wv = e >> 12;
        int o = wv * 32 + (l & 31);
        int c = kf * 16 + (l >> 5) * 8 + j;
        float s = a2g[o] * (1.0f / sqrtf(a2v[o] + EPSBN));
        ((_Float16*)(ws + A2T_OFF))[e] = (_Float16)(a2w[o * 128 + c] * s);
        if (c == 0) ws[BA2_OFF + o] = (a2b[o] - a2m[o]) * s + a2t[o];
        return;
    }
    e -= 16384;
    if (e < 65536) {
        int j = e & 7, l = (e >> 3) & 63, s5 = (e >> 9) & 15, ot = e >> 13;
        int o = ot * 32 + (l & 31);
        int c = s5 * 16 + (l >> 5) * 8 + j;
        float sc = c2g[o] * (1.0f / sqrtf(c2v[o] + EPSBN));
        ((_Float16*)(ws + C2T_OFF))[e] = (_Float16)(c2w[o * 256 + c] * sc);
        if (c == 0) ws[BC2_OFF + o] = (c2b[o] - c2m[o]) * sc + c2t[o];
        return;
    }
    e -= 65536;
    if (e < 32768) {
        int j = e & 7, l = (e >> 3) & 63, s5 = (e >> 9) & 15, ot = e >> 13;
        int o = ot * 32 + (l & 31);
        int c = s5 * 16 + (l >> 5) * 8 + j;
        float sc = c3g[o] * (1.0f / sqrtf(c3v[o] + EPSBN));
        ((_Float16*)(ws + C3H_OFF))[e] = (_Float16)(c3w[o * 256 + c] * sc);
        if (c == 0) ws[BC3_OFF + o] = (c3b[o] - c3m[o]) * sc + c3t[o];
        return;
    }
    e -= 32768;
    if (e < 768)        { fold_one(e,          c4w, c4b, nullptr, nullptr, nullptr, nullptr, ws + C4T_OFF, ws + BC4_OFF, 6, 128, 0); return; }
    e -= 768;
    if (e < 1024)       { ws[GF_OFF + e] = 0.0f; return; }   // GF zero (was memset)
}

// ---------------------------------------------------------------------------
// Kernel 1 (v1, restored): per-point MLP 3->64->64, 4 pts/block.
// ---------------------------------------------------------------------------
__global__ __launch_bounds__(256) void point_mlp_kernel(const float* __restrict__ pts, float* __restrict__ ws)
{
    __shared__ float sh[4][64];
    __shared__ float sx[4][64];
    int lane = threadIdx.x & 63;
    int wv = threadIdx.x >> 6;
    int pid = blockIdx.x * 4 + wv;
    const float* p = pts + pid * 3;
    float x = p[0], y = p[1], z = p[2];
    if (lane == 0) {
        float sq = __fadd_rn(__fadd_rn(__fmul_rn(x, x), __fmul_rn(y, y)), __fmul_rn(z, z));
        ((float4*)(ws + PTS4_OFF))[pid] = make_float4(x, y, z, sq);
    }
    const float* W0T  = ws + W0T_OFF;
    const float* B0   = ws + B0_OFF;
    const float* W1T  = ws + W1T_OFF;
    const float* B1   = ws + B1_OFF;
    const float* A0XT = ws + A0XT_OFF;
    const float* A0FT = ws + A0FT_OFF;
    const float* BA0  = ws + BA0_OFF;

    float h0 = B0[lane];
    h0 = fmaf(x, W0T[lane], h0);
    h0 = fmaf(y, W0T[64 + lane], h0);
    h0 = fmaf(z, W0T[128 + lane], h0);
    h0 = fmaxf(h0, 0.0f);
    sh[wv][lane] = h0;
    __syncthreads();

    float acc = B1[lane];
    #pragma unroll 8
    for (int c = 0; c < 64; ++c) acc = fmaf(W1T[c * 64 + lane], sh[wv][c], acc);
    float x1 = fmaxf(acc, 0.0f);
    sx[wv][lane] = x1;

    float q = __fmul_rn(x, A0XT[lane]);
    q = fmaf(y, A0XT[64 + lane], q);
    q = fmaf(z, A0XT[128 + lane], q);
    ws[Q_OFF + pid * 64 + lane] = q;
    __syncthreads();

    float cacc = q + BA0[lane];
    #pragma unroll 8
    for (int c = 0; c < 64; ++c) cacc = fmaf(A0FT[c * 64 + lane], sx[wv][c], cacc);
    ws[C_OFF + pid * 64 + lane] = cacc;
}

// ---------------------------------------------------------------------------
// Kernel 2 (R11 form + fma fold, proven 80.7us): exact kNN.
// ---------------------------------------------------------------------------
__device__ __forceinline__ float dist2_ref(float xn, float yn, float zn, float sqn, float4 pm)
{
    float dot = __fmul_rn(xn, pm.x);
    dot = __fmaf_rn(yn, pm.y, dot);
    dot = __fmaf_rn(zn, pm.z, dot);
    float s = __fadd_rn(sqn, pm.w);
    // fma(-2,dot,s) == s - round(2*dot) bitwise: 2*dot is exact in fp32.
    return __fmaf_rn(-2.0f, dot, s);
}

#define KNN_CAP 64
__global__ __launch_bounds__(1024) void knn_kernel(float* __restrict__ ws)
{
    __shared__ float gmins[64 * 65];
    __shared__ float bufd[16][72];
    __shared__ int   bufi[16][72];
    __shared__ int   cnt[64];

    const float4* __restrict__ pts4 = (const float4*)(ws + PTS4_OFF);
    int* IDX = (int*)(ws + IDX_OFF);

    const int l     = threadIdx.x & 63;
    const int row   = l;
    const int wvu   = __builtin_amdgcn_readfirstlane(threadIdx.x >> 6);
    const int base  = (blockIdx.x >> 6) << 12;
    const int rbase = blockIdx.x * 64;
    const int r     = rbase + row;

    float4 pn = pts4[r];
    float xn = pn.x, yn = pn.y, zn = pn.z, sqn = pn.w;

    #pragma unroll
    for (int g = 0; g < 4; ++g) {
        const float4* __restrict__ cp = pts4 + base + wvu * 256 + g * 64;
        float mn0 = INFINITY, mn1 = INFINITY, mn2 = INFINITY, mn3 = INFINITY;
        #pragma unroll 4
        for (int i = 0; i < 64; i += 4) {
            mn0 = fminf(mn0, dist2_ref(xn, yn, zn, sqn, cp[i + 0]));
            mn1 = fminf(mn1, dist2_ref(xn, yn, zn, sqn, cp[i + 1]));
            mn2 = fminf(mn2, dist2_ref(xn, yn, zn, sqn, cp[i + 2]));
            mn3 = fminf(mn3, dist2_ref(xn, yn, zn, sqn, cp[i + 3]));
        }
        gmins[row * 65 + wvu * 4 + g] = fminf(fminf(mn0, mn1), fminf(mn2, mn3));
    }
    __syncthreads();

    for (int rr = 0; rr < 4; ++rr) {
        int rw = wvu * 4 + rr;
        float gm = gmins[rw * 65 + l];

        float v = gm;
        #pragma unroll
        for (int k = 2; k <= 64; k <<= 1) {
            #pragma unroll
            for (int j = k >> 1; j > 0; j >>= 1) {
                float o = __shfl_xor(v, j);
                bool mx = (((l & j) != 0) == ((l & k) == 0));
                v = mx ? fmaxf(v, o) : fminf(v, o);
            }
        }
        float tv = __shfl(v, 16);

        unsigned long long qm = __ballot(gm <= tv);

        float4 pr = pts4[rbase + rw];
        float xr = pr.x, yr = pr.y, zr = pr.z, sr = pr.w;

        int cr = 0;
        while (qm) {
            int g = __ffsll((unsigned long long)qm) - 1;
            qm &= qm - 1;
            int ci = g * 64 + l;
            float d = dist2_ref(xr, yr, zr, sr, pts4[base + ci]);
            bool p = (d <= tv);
            unsigned long long mk = __ballot(p);
            int my = __builtin_amdgcn_mbcnt_hi((unsigned)(mk >> 32),
                     __builtin_amdgcn_mbcnt_lo((unsigned)mk, 0));
            int slot = cr + my;
            if (p && slot < KNN_CAP) { bufd[wvu][slot] = d; bufi[wvu][slot] = ci; }
            cr += (int)__popcll(mk);
        }
        if (l == 0) cnt[rw] = cr;

        if (cr <= KNN_CAP) {
            unsigned long long key = ~0ULL;
            if (l < cr) {
                unsigned u = __float_as_uint(bufd[wvu][l]);
                u = (u & 0x80000000u) ? ~u : (u | 0x80000000u);
                key = ((unsigned long long)u << 32) | (unsigned)bufi[wvu][l];
            }
            #pragma unroll
            for (int k = 2; k <= 64; k <<= 1) {
                #pragma unroll
                for (int j = k >> 1; j > 0; j >>= 1) {
                    unsigned long long o = __shfl_xor(key, j);
                    bool mx = (((l & j) != 0) == ((l & k) == 0));
                    key = mx ? (key > o ? key : o) : (key < o ? key : o);
                }
            }
            if (l < 16)
                IDX[(rbase + rw) * 16 + l] = (int)(key & 0xFFFFFFFFu);
        }
    }
    __syncthreads();

    if (threadIdx.x < 64 && cnt[threadIdx.x] > KNN_CAP) {
        int* out = IDX + (rbase + threadIdx.x) * 16;
        float hd[16]; int hi[16];
        #pragma unroll
        for (int t2 = 0; t2 < 16; ++t2) { hd[t2] = INFINITY; hi[t2] = 0; }
        for (int mm = 0; mm < 4096; ++mm) {
            float d = dist2_ref(xn, yn, zn, sqn, pts4[base + mm]);
            if (d < hd[15]) {
                float vd = d; int vi = mm;
                #pragma unroll
                for (int t2 = 0; t2 < 16; ++t2) {
                    bool sm = vd < hd[t2];
                    float td = hd[t2]; int ti = hi[t2];
                    if (sm) { hd[t2] = vd; hi[t2] = vi; vd = td; vi = ti; }
                }
            }
        }
        for (int jj = 0; jj < 16; ++jj) out[jj] = hi[jj];
    }
}

// ---------------------------------------------------------------------------
// Kernel 3 (v3d): a1+a2 fp16 MFMA + FUSED global-feature atomicMax epilogue.
// ---------------------------------------------------------------------------
__device__ __forceinline__ float max16_dpp(float v)
{
    int vi = __float_as_int(v);
    v = fmaxf(v, __int_as_float(__builtin_amdgcn_update_dpp(0, vi, 0xB1, 0xf, 0xf, true)));
    vi = __float_as_int(v);
    v = fmaxf(v, __int_as_float(__builtin_amdgcn_update_dpp(0, vi, 0x4E, 0xf, 0xf, true)));
    vi = __float_as_int(v);
    v = fmaxf(v, __int_as_float(__builtin_amdgcn_update_dpp(0, vi, 0x141, 0xf, 0xf, true)));
    vi = __float_as_int(v);
    v = fmaxf(v, __int_as_float(__builtin_amdgcn_update_dpp(0, vi, 0x140, 0xf, 0xf, true)));
    return v;
}

__device__ __forceinline__ void nbr_stage_g1(
    _Float16* sG1, const float* Cf, const float* Qf,
    int t, int gpt0, int g, int base, int m)
{
    int r = t >> 2, cs = t & 3;
    int gpt = gpt0 + g * 4 + (r >> 4);
    const float4* crow = (const float4*)(Cf + (size_t)(base + m) * 64) + cs * 4;
    const float4* qrow = (const float4*)(Qf + (size_t)gpt * 64) + cs * 4;
    v8h h0, h1;
    #pragma unroll
    for (int u = 0; u < 2; ++u) {
        float4 cv = crow[u], qv = qrow[u];
        h0[u * 4 + 0] = (_Float16)fmaxf(cv.x - qv.x, 0.0f);
        h0[u * 4 + 1] = (_Float16)fmaxf(cv.y - qv.y, 0.0f);
        h0[u * 4 + 2] = (_Float16)fmaxf(cv.z - qv.z, 0.0f);
        h0[u * 4 + 3] = (_Float16)fmaxf(cv.w - qv.w, 0.0f);
    }
    #pragma unroll
    for (int u = 0; u < 2; ++u) {
        float4 cv = crow[2 + u], qv = qrow[2 + u];
        h1[u * 4 + 0] = (_Float16)fmaxf(cv.x - qv.x, 0.0f);
        h1[u * 4 + 1] = (_Float16)fmaxf(cv.y - qv.y, 0.0f);
        h1[u * 4 + 2] = (_Float16)fmaxf(cv.z - qv.z, 0.0f);
        h1[u * 4 + 3] = (_Float16)fmaxf(cv.w - qv.w, 0.0f);
    }
    int rs = r & 7;
    *(v8h*)&sG1[r * 64 + ((cs * 2    ) ^ rs) * 8] = h0;
    *(v8h*)&sG1[r * 64 + ((cs * 2 + 1) ^ rs) * 8] = h1;
}

__global__ __launch_bounds__(256) void nbr_mlp_mfma_kernel(float* __restrict__ ws)
{
    __shared__ __align__(16) unsigned char smem[33792];
    _Float16* sG1   = (_Float16*)smem;
    _Float16* sH1   = (_Float16*)(smem + 8192);
    float*    sPool = (float*)(smem + 24576);
    float*    sB1   = (float*)(smem + 32768);
    float*    sB2   = (float*)(smem + 33280);

    const int t   = threadIdx.x;
    const int l   = t & 63;
    const int w   = t >> 6;
    const int ln  = l & 31;
    const int hi  = l >> 5;
    const int blk = blockIdx.x;
    const int gpt0 = blk * 16;
    const int base = (blk >> 8) << 12;

    const float* Cf = ws + C_OFF;
    const float* Qf = ws + Q_OFF;
    const int* IDX = (const int*)(ws + IDX_OFF);

    if (t < 128) sB1[t] = ws[BA1_OFF + t];
    else         sB2[t - 128] = ws[BA2_OFF + (t - 128)];

    int mi[4];
    {
        int r = t >> 2;
        #pragma unroll
        for (int g = 0; g < 4; ++g)
            mi[g] = IDX[(gpt0 + g * 4 + (r >> 4)) * 16 + (r & 15)];
    }

    v8h fa[4], fa2[8];
    {
        const float4* a1img = (const float4*)(ws + A1T_OFF);
        const float4* a2img = (const float4*)(ws + A2T_OFF);
        #pragma unroll
        for (int kf = 0; kf < 4; ++kf) {
            float4 tmp = a1img[(w * 4 + kf) * 64 + l];
            fa[kf] = *(v8h*)&tmp;
        }
        #pragma unroll
        for (int kf = 0; kf < 8; ++kf) {
            float4 tmp = a2img[(w * 8 + kf) * 64 + l];
            fa2[kf] = *(v8h*)&tmp;
        }
    }

    nbr_stage_g1(sG1, Cf, Qf, t, gpt0, 0, base, mi[0]);
    __syncthreads();

    for (int g = 0; g < 4; ++g) {
        #pragma unroll
        for (int rt = 0; rt < 2; ++rt) {
            int r = rt * 32 + ln, rs = r & 7;
            v16f acc;
            #pragma unroll
            for (int i = 0; i < 16; ++i) acc[i] = 0.0f;
            #pragma unroll
            for (int kf = 0; kf < 4; ++kf) {
                v8h fb = *(const v8h*)&sG1[r * 64 + ((kf * 2 + hi) ^ rs) * 8];
                acc = __builtin_amdgcn_mfma_f32_32x32x16_f16(fa[kf], fb, acc, 0, 0, 0);
            }
            #pragma unroll
            for (int q = 0; q < 4; ++q) {
                float4 b4 = *(const float4*)&sB1[w * 32 + 8 * q + 4 * hi];
                v4h hv;
                hv[0] = (_Float16)fmaxf(acc[q * 4 + 0] + b4.x, 0.0f);
                hv[1] = (_Float16)fmaxf(acc[q * 4 + 1] + b4.y, 0.0f);
                hv[2] = (_Float16)fmaxf(acc[q * 4 + 2] + b4.z, 0.0f);
                hv[3] = (_Float16)fmaxf(acc[q * 4 + 3] + b4.w, 0.0f);
                int gg = w * 4 + q;
                *(v4h*)&sH1[r * 128 + ((gg ^ rs) * 8) + 4 * hi] = hv;
            }
        }
        __syncthreads();

        if (g < 3) nbr_stage_g1(sG1, Cf, Qf, t, gpt0, g + 1, base, mi[g + 1]);

        #pragma unroll
        for (int rt = 0; rt < 2; ++rt) {
            int r = rt * 32 + ln, rs = r & 7;
            v16f acc;
            #pragma unroll
            for (int i = 0; i < 16; ++i) acc[i] = 0.0f;
            #pragma unroll
            for (int kf = 0; kf < 8; ++kf) {
                v8h fb = *(const v8h*)&sH1[r * 128 + ((kf * 2 + hi) ^ rs) * 8];
                acc = __builtin_amdgcn_mfma_f32_32x32x16_f16(fa2[kf], fb, acc, 0, 0, 0);
            }
            #pragma unroll
            for (int i = 0; i < 16; ++i) acc[i] = max16_dpp(acc[i]);
            if ((l & 15) == 0) {
                int p = g * 4 + rt * 2 + ((l >> 4) & 1);
                #pragma unroll
                for (int q = 0; q < 4; ++q) {
                    float4 b4 = *(const float4*)&sB2[w * 32 + 8 * q + 4 * hi];
                    float4 o4;
                    o4.x = fmaxf(acc[q * 4 + 0] + b4.x, 0.0f);
                    o4.y = fmaxf(acc[q * 4 + 1] + b4.y, 0.0f);
                    o4.z = fmaxf(acc[q * 4 + 2] + b4.z, 0.0f);
                    o4.w = fmaxf(acc[q * 4 + 3] + b4.w, 0.0f);
                    int ob = w * 32 + 8 * q + 4 * hi;
                    *(float4*)&sPool[p * 128 + ob] = o4;
                }
            }
        }
        __syncthreads();
    }

    {
        float* LOCAL = ws + LOCAL_OFF;
        const float4* sp4 = (const float4*)sPool;
        #pragma unroll
        for (int u = 0; u < 2; ++u) {
            int e = t + 256 * u;
            int pp = e >> 5, cc = e & 31;
            ((float4*)&LOCAL[(size_t)(gpt0 + pp) * 128])[cc] = sp4[e];
        }
    }

    if (t < 128) {
        float m = 0.0f;
        #pragma unroll
        for (int p = 0; p < 16; ++p) m = fmaxf(m, sPool[p * 128 + t]);
        atomicMax((int*)(ws + GF_OFF) + (blk >> 8) * 128 + t, __float_as_int(m));
    }
}

// ---------------------------------------------------------------------------
// Kernel 5: head c2/c3 fp16 MFMA + c4 fp32 (unchanged — verified).
// ---------------------------------------------------------------------------
__global__ __launch_bounds__(256) void head_mfma_kernel(float* __restrict__ ws, float* __restrict__ out)
{
    __shared__ __align__(16) unsigned char smem[66560];
    _Float16* sF  = (_Float16*)smem;
    float*    sF3 = (float*)smem;
    _Float16* sF2 = (_Float16*)(smem + 33792);

    const int t  = threadIdx.x;
    const int l  = t & 63;
    const int w  = t >> 6;
    const int ln = l & 31;
    const int hi = l >> 5;
    const int gpt0 = blockIdx.x * 64;
    const int b = blockIdx.x >> 6;

    const float4* c2h = (const float4*)(ws + C2T_OFF);
    const float4* c3h = (const float4*)(ws + C3H_OFF);

    {
        int m = t >> 2, cs = t & 3;
        const float4* src = (cs < 2)
            ? (const float4*)(ws + LOCAL_OFF + (size_t)(gpt0 + m) * 128) + cs * 16
            : (const float4*)(ws + GF_OFF + b * 128) + (cs - 2) * 16;
        int c0 = cs * 64;
        #pragma unroll
        for (int u = 0; u < 8; ++u) {
            float4 a0 = src[u * 2], a1 = src[u * 2 + 1];
            v8h h;
            h[0] = (_Float16)a0.x; h[1] = (_Float16)a0.y;
            h[2] = (_Float16)a0.z; h[3] = (_Float16)a0.w;
            h[4] = (_Float16)a1.x; h[5] = (_Float16)a1.y;
            h[6] = (_Float16)a1.z; h[7] = (_Float16)a1.w;
            int g = ((c0 >> 3) + u) ^ (m & 31);
            *(v8h*)&sF[m * 256 + g * 8] = h;
        }
    }
    __syncthreads();

    #pragma unroll
    for (int ot = 0; ot < 2; ++ot) {
        int ot2 = 2 * w + ot;
        v8h fa[16];
        #pragma unroll
        for (int s = 0; s < 16; ++s) {
            float4 tmp = c2h[(ot2 * 16 + s) * 64 + l];
            fa[s] = *(v8h*)&tmp;
        }
        float b2[16];
        #pragma unroll
        for (int i = 0; i < 16; ++i)
            b2[i] = ws[BC2_OFF + ot2 * 32 + (i & 3) + 8 * (i >> 2) + 4 * hi];
        #pragma unroll
        for (int mt = 0; mt < 2; ++mt) {
            int m = mt * 32 + ln;
            v16f acc;
            #pragma unroll
            for (int i = 0; i < 16; ++i) acc[i] = 0.0f;
            #pragma unroll
            for (int s = 0; s < 16; ++s) {
                v8h fb = *(const v8h*)&sF[m * 256 + (((2 * s + hi) ^ ln) * 8)];
                acc = __builtin_amdgcn_mfma_f32_32x32x16_f16(fa[s], fb, acc, 0, 0, 0);
            }
            #pragma unroll
            for (int q = 0; q < 4; ++q) {
                v4h hv;
                #pragma unroll
                for (int j = 0; j < 4; ++j)
                    hv[j] = (_Float16)fmaxf(acc[q * 4 + j] + b2[q * 4 + j], 0.0f);
                *(v4h*)&sF2[m * 256 + (((ot2 * 4 + q) ^ ln) * 8) + 4 * hi] = hv;
            }
        }
    }
    __syncthreads();

    {
        v8h fa[16];
        #pragma unroll
        for (int s = 0; s < 16; ++s) {
            float4 tmp = c3h[(w * 16 + s) * 64 + l];
            fa[s] = *(v8h*)&tmp;
        }
        float b3[16];
        #pragma unroll
        for (int i = 0; i < 16; ++i)
            b3[i] = ws[BC3_OFF + w * 32 + (i & 3) + 8 * (i >> 2) + 4 * hi];
        #pragma unroll
        for (int mt = 0; mt < 2; ++mt) {
            int m = mt * 32 + ln;
            v16f acc;
            #pragma unroll
            for (int i = 0; i < 16; ++i) acc[i] = 0.0f;
            #pragma unroll
            for (int s = 0; s < 16; ++s) {
                v8h fb = *(const v8h*)&sF2[m * 256 + (((2 * s + hi) ^ ln) * 8)];
                acc = __builtin_amdgcn_mfma_f32_32x32x16_f16(fa[s], fb, acc, 0, 0, 0);
            }
            #pragma unroll
            for (int q = 0; q < 4; ++q) {
                float4 hv;
                hv.x = fmaxf(acc[q * 4 + 0] + b3[q * 4 + 0], 0.0f);
                hv.y = fmaxf(acc[q * 4 + 1] + b3[q * 4 + 1], 0.0f);
                hv.z = fmaxf(acc[q * 4 + 2] + b3[q * 4 + 2], 0.0f);
                hv.w = fmaxf(acc[q * 4 + 3] + b3[q * 4 + 3], 0.0f);
                *(float4*)&sF3[m * 132 + w * 32 + q * 8 + 4 * hi] = hv;
            }
        }
    }
    __syncthreads();

    const float* C4T = ws + C4T_OFF;
    for (int mo = t; mo < 384; mo += 256) {
        int m = mo / 6, o = mo - m * 6;
        float a = ws[BC4_OFF + o];
        const float4* f4 = (const float4*)(sF3 + m * 132);
        #pragma unroll 8
        for (int kq = 0; kq < 32; ++kq) {
            float4 f = f4[kq];
            a = fmaf(f.x, C4T[(kq * 4 + 0) * 6 + o], a);
            a = fmaf(f.y, C4T[(kq * 4 + 1) * 6 + o], a);
            a = fmaf(f.z, C4T[(kq * 4 + 2) * 6 + o], a);
            a = fmaf(f.w, C4T[(kq * 4 + 3) * 6 + o], a);
        }
        out[(size_t)(gpt0 + m) * 6 + o] = a;
    }
}

// ---------------------------------------------------------------------------
extern "C" void kernel_launch(void* const* d_in, const int* in_sizes, int n_in,
                              void* d_out, int out_size, void* d_ws, size_t ws_size,
                              hipStream_t stream)
{
    const float* pts = (const float*)d_in[0];
    float* ws = (float*)d_ws;
    float* out = (float*)d_out;

    fold_kernel<<<521, 256, 0, stream>>>(
        (const float*)d_in[1],  (const float*)d_in[2],  (const float*)d_in[3],  (const float*)d_in[4],  (const float*)d_in[5],  (const float*)d_in[6],
        (const float*)d_in[7],  (const float*)d_in[8],  (const float*)d_in[9],  (const float*)d_in[10], (const float*)d_in[11], (const float*)d_in[12],
        (const float*)d_in[13], (const float*)d_in[14], (const float*)d_in[15], (const float*)d_in[16], (const float*)d_in[17], (const float*)d_in[18],
        (const float*)d_in[19], (const float*)d_in[20], (const float*)d_in[21], (const float*)d_in[22], (const float*)d_in[23], (const float*)d_in[24],
        (const float*)d_in[25], (const float*)d_in[26], (const float*)d_in[27], (const float*)d_in[28], (const float*)d_in[29], (const float*)d_in[30],
        (const float*)d_in[31], (const float*)d_in[32], (const float*)d_in[33], (const float*)d_in[34], (const float*)d_in[35], (const float*)d_in[36],
        (const float*)d_in[37], (const float*)d_in[38], (const float*)d_in[39], (const float*)d_in[40], (const float*)d_in[41], (const float*)d_in[42],
        (const float*)d_in[43], (const float*)d_in[44],
        ws);

    point_mlp_kernel<<<8192, 256, 0, stream>>>(pts, ws);
    knn_kernel<<<512, 1024, 0, stream>>>(ws);
    nbr_mlp_mfma_kernel<<<2048, 256, 0, stream>>>(ws);
    head_mfma_kernel<<<512, 256, 0, stream>>>(ws, out);
}